// Round 1
// baseline (1121.067 us; speedup 1.0000x reference)
//
#include <hip/hip_runtime.h>
#include <hip/hip_bf16.h>
#include <math.h>

// ---------------------------------------------------------------------------
// ZoomMIL: hierarchical gated-attention MIL with top-k zoom.
// Round 1: correct fp32 baseline. GEMMs are 64x64x16 LDS-tiled fp32 (4x4
// microtile). Row-gathers folded into GEMM A-load via rowmap. Top-k via
// single-block bitonic sort on packed (score,idx) u64 keys.
// ---------------------------------------------------------------------------

#define GBS 256  // gemm block size

// C[M x N] = op(A[rowmap] [M x K]) * B[K x N] + bias, optional relu.
// grid = (N/64, M/64), block = 256. lda/ldb/ldc in elements.
__global__ __launch_bounds__(GBS) void zm_gemm(
    const float* __restrict__ A, int lda,
    const int* __restrict__ rowmap,
    const float* __restrict__ B, int ldb,
    const float* __restrict__ bias,
    float* __restrict__ C, int ldc,
    int K, int relu)
{
    __shared__ float As[16][68];  // [k][row], padded
    __shared__ float Bs[16][68];  // [k][col], padded

    const int tid = threadIdx.x;
    const int tx = tid & 15;       // col group
    const int ty = tid >> 4;       // row group
    const int brow = blockIdx.y << 6;
    const int bcol = blockIdx.x << 6;

    // A-tile load: thread -> (row ar, 4 cols starting at ac)
    const int ar = tid >> 2;            // 0..63
    const int ac = (tid & 3) << 2;      // 0,4,8,12
    int arow = brow + ar;
    if (rowmap) arow = rowmap[arow];
    const float* Aptr = A + (size_t)arow * lda;

    // B-tile load: thread -> (row br, 4 cols at bc)
    const int br = tid >> 4;            // 0..15
    const int bc = (tid & 15) << 2;     // 0..60

    float acc[4][4] = {};

    for (int k0 = 0; k0 < K; k0 += 16) {
        float4 av = *(const float4*)(Aptr + k0 + ac);
        float4 bv = *(const float4*)(B + (size_t)(k0 + br) * ldb + bcol + bc);
        As[ac + 0][ar] = av.x;
        As[ac + 1][ar] = av.y;
        As[ac + 2][ar] = av.z;
        As[ac + 3][ar] = av.w;
        *(float4*)&Bs[br][bc] = bv;
        __syncthreads();
#pragma unroll
        for (int kk = 0; kk < 16; kk++) {
            float4 a4 = *(const float4*)&As[kk][ty << 2];
            float4 b4 = *(const float4*)&Bs[kk][tx << 2];
            float a[4] = {a4.x, a4.y, a4.z, a4.w};
            float b[4] = {b4.x, b4.y, b4.z, b4.w};
#pragma unroll
            for (int i = 0; i < 4; i++)
#pragma unroll
                for (int j = 0; j < 4; j++)
                    acc[i][j] += a[i] * b[j];
        }
        __syncthreads();
    }

#pragma unroll
    for (int i = 0; i < 4; i++) {
        int row = brow + (ty << 2) + i;
        float4 out;
        float* o = &out.x;
#pragma unroll
        for (int j = 0; j < 4; j++) {
            float v = acc[i][j];
            if (bias) v += bias[bcol + (tx << 2) + j];
            if (relu) v = fmaxf(v, 0.0f);
            o[j] = v;
        }
        *(float4*)&C[(size_t)row * ldc + bcol + (tx << 2)] = out;
    }
}

// s[row] = sum_h tanh(T[row][h]) * sigmoid(T[row][256+h]) * Wc[h] + bc[0]
// one wave per row; grid = rows/4, block = 256
__global__ __launch_bounds__(256) void zm_ga_combine(
    const float* __restrict__ T, int ldT,
    const float* __restrict__ Wc, const float* __restrict__ bc,
    float* __restrict__ sout)
{
    const int tid = threadIdx.x;
    const int wave = tid >> 6, lane = tid & 63;
    const int row = blockIdx.x * 4 + wave;
    const float* tr = T + (size_t)row * ldT;
    float p = 0.0f;
#pragma unroll
    for (int j = 0; j < 4; j++) {
        int h = lane + 64 * j;
        float a = tanhf(tr[h]);
        float g = 1.0f / (1.0f + expf(-tr[256 + h]));
        p += a * g * Wc[h];
    }
    for (int o = 32; o > 0; o >>= 1) p += __shfl_down(p, o);
    if (lane == 0) sout[row] = p + bc[0];
}

// top-256 of s[0..n) (n = 4096 or 1024, pow2), indices sorted ascending.
// Matches jax.lax.top_k tie-break (lower index wins). Single block of 512.
__global__ __launch_bounds__(512) void zm_topk(
    const float* __restrict__ s, int n, int* __restrict__ idx_out)
{
    __shared__ unsigned long long keys[4096];
    const int bs = 512;
    const int tid = threadIdx.x;

    for (int i = tid; i < n; i += bs) {
        unsigned int u = __float_as_uint(s[i]);
        u = (u & 0x80000000u) ? ~u : (u | 0x80000000u);  // order-preserving map
        // primary: score descending (~u ascending); secondary: idx ascending
        keys[i] = ((unsigned long long)(~u) << 32) | (unsigned int)i;
    }
    __syncthreads();

    for (int k2 = 2; k2 <= n; k2 <<= 1) {
        for (int j = k2 >> 1; j > 0; j >>= 1) {
            for (int i = tid; i < n; i += bs) {
                int ixj = i ^ j;
                if (ixj > i) {
                    unsigned long long a = keys[i], b = keys[ixj];
                    bool up = ((i & k2) == 0);
                    if ((a > b) == up) { keys[i] = b; keys[ixj] = a; }
                }
            }
            __syncthreads();
        }
    }

    // keys[0..255] are the top-256; now sort their indices ascending.
    int v = 0;
    if (tid < 256) v = (int)(keys[tid] & 0xffffffffu);
    __syncthreads();
    int* ik = (int*)keys;
    if (tid < 256) ik[tid] = v;
    __syncthreads();

    for (int k2 = 2; k2 <= 256; k2 <<= 1) {
        for (int j = k2 >> 1; j > 0; j >>= 1) {
            for (int i = tid; i < 256; i += bs) {
                int ixj = i ^ j;
                if (ixj > i) {
                    int a = ik[i], b = ik[ixj];
                    bool up = ((i & k2) == 0);
                    if ((a > b) == up) { ik[i] = b; ik[ixj] = a; }
                }
            }
            __syncthreads();
        }
    }
    if (tid < 256) idx_out[tid] = ik[tid];
}

// rowmap2[j] = idx1[j/4]*4 + j%4   (j in [0,1024))
__global__ void zm_mapgen2(const int* __restrict__ idx1, int* __restrict__ rm)
{
    int j = threadIdx.x;
    rm[j] = idx1[j >> 2] * 4 + (j & 3);
}

// rowmap3[j]: t = idx2[j/4]*4 + j%4;  rm[j] = idx1[t/16]*16 + t%16
__global__ void zm_mapgen3(const int* __restrict__ idx1, const int* __restrict__ idx2,
                           int* __restrict__ rm)
{
    int j = threadIdx.x;
    int t = idx2[j >> 2] * 4 + (j & 3);
    rm[j] = idx1[t >> 4] * 16 + (t & 15);
}

// softmax stats: out[0] = max(s), out[1] = sum exp(s - max). one block.
__global__ __launch_bounds__(256) void zm_stats(
    const float* __restrict__ s, int n, float* __restrict__ out)
{
    __shared__ float red[256];
    const int tid = threadIdx.x;
    float mx = -3.4e38f;
    for (int i = tid; i < n; i += 256) mx = fmaxf(mx, s[i]);
    red[tid] = mx;
    __syncthreads();
    for (int o = 128; o > 0; o >>= 1) {
        if (tid < o) red[tid] = fmaxf(red[tid], red[tid + o]);
        __syncthreads();
    }
    mx = red[0];
    __syncthreads();
    float z = 0.0f;
    for (int i = tid; i < n; i += 256) z += expf(s[i] - mx);
    red[tid] = z;
    __syncthreads();
    for (int o = 128; o > 0; o >>= 1) {
        if (tid < o) red[tid] += red[tid + o];
        __syncthreads();
    }
    if (tid == 0) { out[0] = mx; out[1] = red[0]; }
}

__global__ void zm_zero(float* __restrict__ p, int n)
{
    int i = blockIdx.x * blockDim.x + threadIdx.x;
    if (i < n) p[i] = 0.0f;
}

// Mout[f] += sum_rows softmax(s)[row] * h[row][f]; block handles `rpb` rows.
__global__ __launch_bounds__(256) void zm_wsum(
    const float* __restrict__ h, const float* __restrict__ s,
    const float* __restrict__ st, int rpb, float* __restrict__ Mout)
{
    const int tid = threadIdx.x;
    const int r0 = blockIdx.x * rpb;
    const float mx = st[0];
    const float invZ = 1.0f / st[1];
    float a0 = 0.0f, a1 = 0.0f;
    for (int r = 0; r < rpb; r++) {
        int n = r0 + r;
        float w = expf(s[n] - mx) * invZ;
        a0 += w * h[(size_t)n * 512 + tid];
        a1 += w * h[(size_t)n * 512 + 256 + tid];
    }
    atomicAdd(&Mout[tid], a0);
    atomicAdd(&Mout[tid + 256], a1);
}

// logits[c] = sum_f M[f] * Wh[f][c] + bh[c]; one block, wave c per class.
__global__ __launch_bounds__(256) void zm_logits(
    const float* __restrict__ M, const float* __restrict__ Wh,
    const float* __restrict__ bh, float* __restrict__ out)
{
    const int tid = threadIdx.x;
    const int c = tid >> 6, lane = tid & 63;
    float p = 0.0f;
    for (int f = lane; f < 512; f += 64) p += M[f] * Wh[f * 4 + c];
    for (int o = 32; o > 0; o >>= 1) p += __shfl_down(p, o);
    if (lane == 0) out[c] = p + bh[c];
}

extern "C" void kernel_launch(void* const* d_in, const int* in_sizes, int n_in,
                              void* d_out, int out_size, void* d_ws, size_t ws_size,
                              hipStream_t stream)
{
    const float* x1   = (const float*)d_in[0];   // 4096 x 1024
    const float* x2   = (const float*)d_in[1];   // 16384 x 1024
    const float* x3   = (const float*)d_in[2];   // 65536 x 1024
    const float* fcW  = (const float*)d_in[3];   // 3 x 1024 x 512
    const float* fcb  = (const float*)d_in[4];   // 3 x 512
    const float* gaWa = (const float*)d_in[5];   // 5 x 512 x 256
    const float* gaba = (const float*)d_in[6];   // 5 x 256
    const float* gaWb = (const float*)d_in[7];   // 5 x 512 x 256
    const float* gabb = (const float*)d_in[8];   // 5 x 256
    const float* gaWc = (const float*)d_in[9];   // 5 x 256 x 1
    const float* gabc = (const float*)d_in[10];  // 5 x 1
    const float* Wh   = (const float*)d_in[11];  // 512 x 4
    const float* bh   = (const float*)d_in[12];  // 4
    float* out = (float*)d_out;                  // 1 x 4

    const int FH = 512 * 256;      // gaWa/gaWb per-head stride
    const int FCW = 1024 * 512;    // fcW per-level stride

    // workspace layout (floats)
    float* ws = (float*)d_ws;
    float* h1   = ws;                      // 4096*512
    float* T1   = h1 + 4096 * 512;         // 4096*1024 (reused as T2/T3)
    float* h2   = T1 + 4096 * 1024;        // 1024*512
    float* h3   = h2 + 1024 * 512;         // 1024*512
    float* s1   = h3 + 1024 * 512;         // 4096
    float* s1a  = s1 + 4096;               // 4096
    float* s2   = s1a + 4096;              // 1024
    float* s2a  = s2 + 1024;               // 1024
    float* s3   = s2a + 1024;              // 1024
    float* st   = s3 + 1024;               // 8 (3x {max,Z})
    float* Mbuf = st + 8;                  // 512
    int* idx1 = (int*)(Mbuf + 512);        // 256
    int* idx2 = idx1 + 256;                // 256
    int* rm2  = idx2 + 256;                // 1024
    int* rm3  = rm2 + 1024;                // 1024

    // ---- low mag ----
    // h1 = relu(x1 @ fcW[0] + fcb[0])
    zm_gemm<<<dim3(8, 64), GBS, 0, stream>>>(x1, 1024, nullptr, fcW, 512, fcb,
                                             h1, 512, 1024, 1);
    zm_zero<<<1, 512, 0, stream>>>(Mbuf, 512);

    // T1 cols: [0..255]=a0 pre, [256..511]=g0 pre, [512..767]=a3, [768..1023]=g3
    zm_gemm<<<dim3(4, 64), GBS, 0, stream>>>(h1, 512, nullptr, gaWa + 0 * FH, 256,
                                             gaba + 0 * 256, T1 + 0, 1024, 512, 0);
    zm_gemm<<<dim3(4, 64), GBS, 0, stream>>>(h1, 512, nullptr, gaWb + 0 * FH, 256,
                                             gabb + 0 * 256, T1 + 256, 1024, 512, 0);
    zm_gemm<<<dim3(4, 64), GBS, 0, stream>>>(h1, 512, nullptr, gaWa + 3 * FH, 256,
                                             gaba + 3 * 256, T1 + 512, 1024, 512, 0);
    zm_gemm<<<dim3(4, 64), GBS, 0, stream>>>(h1, 512, nullptr, gaWb + 3 * FH, 256,
                                             gabb + 3 * 256, T1 + 768, 1024, 512, 0);
    zm_ga_combine<<<1024, 256, 0, stream>>>(T1, 1024, gaWc + 0 * 256, gabc + 0, s1);
    zm_ga_combine<<<1024, 256, 0, stream>>>(T1 + 512, 1024, gaWc + 3 * 256, gabc + 3, s1a);

    zm_topk<<<1, 512, 0, stream>>>(s1a, 4096, idx1);
    zm_mapgen2<<<1, 1024, 0, stream>>>(idx1, rm2);

    // ---- mid mag ----
    zm_gemm<<<dim3(8, 16), GBS, 0, stream>>>(x2, 1024, rm2, fcW + 1 * FCW, 512,
                                             fcb + 512, h2, 512, 1024, 1);
    zm_gemm<<<dim3(4, 16), GBS, 0, stream>>>(h2, 512, nullptr, gaWa + 1 * FH, 256,
                                             gaba + 1 * 256, T1 + 0, 1024, 512, 0);
    zm_gemm<<<dim3(4, 16), GBS, 0, stream>>>(h2, 512, nullptr, gaWb + 1 * FH, 256,
                                             gabb + 1 * 256, T1 + 256, 1024, 512, 0);
    zm_gemm<<<dim3(4, 16), GBS, 0, stream>>>(h2, 512, nullptr, gaWa + 4 * FH, 256,
                                             gaba + 4 * 256, T1 + 512, 1024, 512, 0);
    zm_gemm<<<dim3(4, 16), GBS, 0, stream>>>(h2, 512, nullptr, gaWb + 4 * FH, 256,
                                             gabb + 4 * 256, T1 + 768, 1024, 512, 0);
    zm_ga_combine<<<256, 256, 0, stream>>>(T1, 1024, gaWc + 1 * 256, gabc + 1, s2);
    zm_ga_combine<<<256, 256, 0, stream>>>(T1 + 512, 1024, gaWc + 4 * 256, gabc + 4, s2a);

    zm_topk<<<1, 512, 0, stream>>>(s2a, 1024, idx2);
    zm_mapgen3<<<1, 1024, 0, stream>>>(idx1, idx2, rm3);

    // ---- high mag ----
    zm_gemm<<<dim3(8, 16), GBS, 0, stream>>>(x3, 1024, rm3, fcW + 2 * FCW, 512,
                                             fcb + 1024, h3, 512, 1024, 1);
    zm_gemm<<<dim3(4, 16), GBS, 0, stream>>>(h3, 512, nullptr, gaWa + 2 * FH, 256,
                                             gaba + 2 * 256, T1 + 0, 512, 512, 0);
    zm_gemm<<<dim3(4, 16), GBS, 0, stream>>>(h3, 512, nullptr, gaWb + 2 * FH, 256,
                                             gabb + 2 * 256, T1 + 256, 512, 512, 0);
    zm_ga_combine<<<256, 256, 0, stream>>>(T1, 512, gaWc + 2 * 256, gabc + 2, s3);

    // ---- pooling + head ----
    zm_stats<<<1, 256, 0, stream>>>(s1, 4096, st + 0);
    zm_stats<<<1, 256, 0, stream>>>(s2, 1024, st + 2);
    zm_stats<<<1, 256, 0, stream>>>(s3, 1024, st + 4);
    zm_wsum<<<64, 256, 0, stream>>>(h1, s1, st + 0, 64, Mbuf);
    zm_wsum<<<16, 256, 0, stream>>>(h2, s2, st + 2, 64, Mbuf);
    zm_wsum<<<16, 256, 0, stream>>>(h3, s3, st + 4, 64, Mbuf);
    zm_logits<<<1, 256, 0, stream>>>(Mbuf, Wh, bh, out);
}

// Round 2
// 724.300 us; speedup vs baseline: 1.5478x; 1.5478x over previous
//
#include <hip/hip_runtime.h>
#include <hip/hip_bf16.h>
#include <math.h>

// ---------------------------------------------------------------------------
// ZoomMIL round 2: bf16 MFMA GEMMs (16x16x32), weight transpose-pack to
// [N][K] bf16, gather folded into A-staging, dual fp32+bf16 h outputs.
// ---------------------------------------------------------------------------

typedef __attribute__((ext_vector_type(8))) short short8;
typedef __attribute__((ext_vector_type(4))) float float4a;

__device__ __forceinline__ ushort f2bf(float f) {
    unsigned u = __float_as_uint(f);
    return (ushort)((u + 0x7fffu + ((u >> 16) & 1u)) >> 16);
}

// ---------------------------------------------------------------------------
// MFMA GEMM: C[M x N] = op(A[rowmap][M x K]) @ B[K x N] + bias, optional relu.
// Bt is B pre-transposed+bf16: [N][K], row stride K.
// Tile: BM=128, BN=64, BK=32. Block 256 = 4 waves (2x2 over tile).
// ABF16=0: A fp32 (converted in staging). ABF16=1: A bf16 (ushort).
// ---------------------------------------------------------------------------
template<int ABF16>
__global__ __launch_bounds__(256) void zm_mgemm(
    const void* __restrict__ Av, int lda,
    const int* __restrict__ rowmap,
    const ushort* __restrict__ Bt,
    const float* __restrict__ bias,
    float* __restrict__ C, int ldc,
    ushort* __restrict__ Cb,
    int K, int relu)
{
    __shared__ ushort As[128 * 40];  // [row][k], pitch 40 (80B: 16B-aligned, 2-way banks)
    __shared__ ushort Bs[64 * 40];   // [n][k]

    const int tid = threadIdx.x;
    const int brow = blockIdx.y << 7;   // *128
    const int bcol = blockIdx.x << 6;   // *64

    // staging assignments
    const int sr = tid >> 1;            // A row 0..127
    const int sk = (tid & 1) << 4;      // A k-half: 0 or 16
    int arow = brow + sr;
    if (rowmap) arow = rowmap[arow];
    const float*  Af = (const float*)Av;
    const ushort* Ab = (const ushort*)Av;

    const int bn = tid >> 2;            // B n 0..63
    const int bk = (tid & 3) << 3;      // B k: 0,8,16,24
    const ushort* Bp = Bt + (size_t)(bcol + bn) * K + bk;

    // compute assignments
    const int w    = tid >> 6;
    const int wm   = (w >> 1) << 6;     // wave row offset: 0/64
    const int wn   = (w & 1) << 5;      // wave col offset: 0/32
    const int lane = tid & 63;
    const int lm   = lane & 15;
    const int lq   = lane >> 4;

    float4a acc[4][2] = {};

    for (int k0 = 0; k0 < K; k0 += 32) {
        // ---- stage A ----
        if (ABF16) {
            const ushort* ap = Ab + (size_t)arow * lda + k0 + sk;
            uint4 w0 = *(const uint4*)ap;
            uint4 w1 = *(const uint4*)(ap + 8);
            *(uint4*)&As[sr * 40 + sk]     = w0;
            *(uint4*)&As[sr * 40 + sk + 8] = w1;
        } else {
            const float* ap = Af + (size_t)arow * lda + k0 + sk;
            float4 v0 = *(const float4*)ap;
            float4 v1 = *(const float4*)(ap + 4);
            float4 v2 = *(const float4*)(ap + 8);
            float4 v3 = *(const float4*)(ap + 12);
            uint4 p0, p1;
            p0.x = (uint)f2bf(v0.x) | ((uint)f2bf(v0.y) << 16);
            p0.y = (uint)f2bf(v0.z) | ((uint)f2bf(v0.w) << 16);
            p0.z = (uint)f2bf(v1.x) | ((uint)f2bf(v1.y) << 16);
            p0.w = (uint)f2bf(v1.z) | ((uint)f2bf(v1.w) << 16);
            p1.x = (uint)f2bf(v2.x) | ((uint)f2bf(v2.y) << 16);
            p1.y = (uint)f2bf(v2.z) | ((uint)f2bf(v2.w) << 16);
            p1.z = (uint)f2bf(v3.x) | ((uint)f2bf(v3.y) << 16);
            p1.w = (uint)f2bf(v3.z) | ((uint)f2bf(v3.w) << 16);
            *(uint4*)&As[sr * 40 + sk]     = p0;
            *(uint4*)&As[sr * 40 + sk + 8] = p1;
        }
        // ---- stage B ----
        *(uint4*)&Bs[bn * 40 + bk] = *(const uint4*)(Bp + k0);
        __syncthreads();

        // ---- MFMA ----
        short8 afr[4], bfr[2];
#pragma unroll
        for (int mt = 0; mt < 4; mt++)
            afr[mt] = *(const short8*)&As[(wm + mt * 16 + lm) * 40 + lq * 8];
#pragma unroll
        for (int nt = 0; nt < 2; nt++)
            bfr[nt] = *(const short8*)&Bs[(wn + nt * 16 + lm) * 40 + lq * 8];
#pragma unroll
        for (int mt = 0; mt < 4; mt++)
#pragma unroll
            for (int nt = 0; nt < 2; nt++)
                acc[mt][nt] = __builtin_amdgcn_mfma_f32_16x16x32_bf16(
                    afr[mt], bfr[nt], acc[mt][nt], 0, 0, 0);
        __syncthreads();
    }

    // ---- epilogue: C/D layout col=lane&15, row=quad*4+reg ----
#pragma unroll
    for (int mt = 0; mt < 4; mt++) {
#pragma unroll
        for (int nt = 0; nt < 2; nt++) {
            int gc = bcol + wn + nt * 16 + lm;
            float bv = bias ? bias[gc] : 0.0f;
#pragma unroll
            for (int r = 0; r < 4; r++) {
                int gr = brow + wm + mt * 16 + lq * 4 + r;
                float v = acc[mt][nt][r] + bv;
                if (relu) v = fmaxf(v, 0.0f);
                C[(size_t)gr * ldc + gc] = v;
                if (Cb) Cb[(size_t)gr * ldc + gc] = f2bf(v);
            }
        }
    }
}

// ---------------------------------------------------------------------------
// Weight transpose-pack: fp32 [K][N] -> bf16 [N][K].
// blocks 0..1535: fcW (3 mats 1024x512 -> fc_t[i] 512x1024)
// blocks 1536..2815: gating (10 mats 512x256 -> g_low/g_mid/g_high rows)
// ---------------------------------------------------------------------------
__global__ __launch_bounds__(256) void zm_pack(
    const float* __restrict__ fcW,
    const float* __restrict__ gaWa, const float* __restrict__ gaWb,
    ushort* __restrict__ fc_t, ushort* __restrict__ g_low,
    ushort* __restrict__ g_mid, ushort* __restrict__ g_high)
{
    __shared__ ushort tile[32][33];
    const int b = blockIdx.x;
    const float* src; int sld; ushort* dst; int dld; int k0, n0, drow;
    if (b < 1536) {
        int mat = b >> 9, rem = b & 511;
        int tk = rem >> 4, tn = rem & 15;
        src = fcW + (size_t)mat * 1024 * 512; sld = 512;
        dst = fc_t + (size_t)mat * 512 * 1024; dld = 1024;
        k0 = tk * 32; n0 = tn * 32; drow = 0;
    } else {
        int idx = b - 1536;
        int mat = idx >> 7, rem = idx & 127;
        int tk = rem >> 3, tn = rem & 7;
        int head = mat >> 1, br = mat & 1;
        src = (br ? gaWb : gaWa) + (size_t)head * 512 * 256; sld = 256;
        ushort* base; int off;
        if (head == 0)      { base = g_low;  off = 0;   }
        else if (head == 1) { base = g_mid;  off = 0;   }
        else if (head == 2) { base = g_high; off = 0;   }
        else if (head == 3) { base = g_low;  off = 512; }
        else                { base = g_mid;  off = 512; }
        dst = base; dld = 512;
        k0 = tk * 32; n0 = tn * 32; drow = off + br * 256;
    }
    const int t = threadIdx.x;
    const int c = t & 31, r8 = t >> 5;
#pragma unroll
    for (int it = 0; it < 4; it++) {
        int r = r8 + it * 8;
        tile[r][c] = f2bf(src[(size_t)(k0 + r) * sld + n0 + c]);
    }
    __syncthreads();
#pragma unroll
    for (int it = 0; it < 4; it++) {
        int r = r8 + it * 8;
        dst[(size_t)(drow + n0 + r) * dld + k0 + c] = tile[c][r];
    }
}

// pack gating biases: [a g a g] per level (1024 threads)
__global__ void zm_packbias(const float* __restrict__ gaba,
                            const float* __restrict__ gabb,
                            float* __restrict__ bl, float* __restrict__ bm,
                            float* __restrict__ bhg)
{
    int t = threadIdx.x;
    int seg = t >> 8, i = t & 255;
    const float* sl = (seg == 0) ? gaba : (seg == 1) ? gabb
                    : (seg == 2) ? gaba + 3 * 256 : gabb + 3 * 256;
    bl[t] = sl[i];
    const float* sm = (seg == 0) ? gaba + 256 : (seg == 1) ? gabb + 256
                    : (seg == 2) ? gaba + 4 * 256 : gabb + 4 * 256;
    bm[t] = sm[i];
    if (t < 512) bhg[t] = (seg == 0) ? gaba[2 * 256 + i] : gabb[2 * 256 + i];
}

// s[row] = sum_h tanh(T[row][h]) * sigmoid(T[row][256+h]) * Wc[h] + bc[0]
__global__ __launch_bounds__(256) void zm_ga_combine(
    const float* __restrict__ T, int ldT,
    const float* __restrict__ Wc, const float* __restrict__ bc,
    float* __restrict__ sout)
{
    const int tid = threadIdx.x;
    const int wave = tid >> 6, lane = tid & 63;
    const int row = blockIdx.x * 4 + wave;
    const float* tr = T + (size_t)row * ldT;
    float p = 0.0f;
#pragma unroll
    for (int j = 0; j < 4; j++) {
        int h = lane + 64 * j;
        float a = tanhf(tr[h]);
        float g = 1.0f / (1.0f + expf(-tr[256 + h]));
        p += a * g * Wc[h];
    }
    for (int o = 32; o > 0; o >>= 1) p += __shfl_down(p, o);
    if (lane == 0) sout[row] = p + bc[0];
}

// top-256 of s[0..n), n pow2; indices out sorted ascending.
__global__ __launch_bounds__(512) void zm_topk(
    const float* __restrict__ s, int n, int* __restrict__ idx_out)
{
    __shared__ unsigned long long keys[4096];
    const int bs = 512;
    const int tid = threadIdx.x;

    for (int i = tid; i < n; i += bs) {
        unsigned int u = __float_as_uint(s[i]);
        u = (u & 0x80000000u) ? ~u : (u | 0x80000000u);
        keys[i] = ((unsigned long long)(~u) << 32) | (unsigned int)i;
    }
    __syncthreads();

    for (int k2 = 2; k2 <= n; k2 <<= 1) {
        for (int j = k2 >> 1; j > 0; j >>= 1) {
            for (int i = tid; i < n; i += bs) {
                int ixj = i ^ j;
                if (ixj > i) {
                    unsigned long long a = keys[i], b = keys[ixj];
                    bool up = ((i & k2) == 0);
                    if ((a > b) == up) { keys[i] = b; keys[ixj] = a; }
                }
            }
            __syncthreads();
        }
    }

    int v = 0;
    if (tid < 256) v = (int)(keys[tid] & 0xffffffffu);
    __syncthreads();
    int* ik = (int*)keys;
    if (tid < 256) ik[tid] = v;
    __syncthreads();

    for (int k2 = 2; k2 <= 256; k2 <<= 1) {
        for (int j = k2 >> 1; j > 0; j >>= 1) {
            for (int i = tid; i < 256; i += bs) {
                int ixj = i ^ j;
                if (ixj > i) {
                    int a = ik[i], b = ik[ixj];
                    bool up = ((i & k2) == 0);
                    if ((a > b) == up) { ik[i] = b; ik[ixj] = a; }
                }
            }
            __syncthreads();
        }
    }
    if (tid < 256) idx_out[tid] = ik[tid];
}

__global__ void zm_mapgen2(const int* __restrict__ idx1, int* __restrict__ rm)
{
    int j = threadIdx.x;
    rm[j] = idx1[j >> 2] * 4 + (j & 3);
}

__global__ void zm_mapgen3(const int* __restrict__ idx1, const int* __restrict__ idx2,
                           int* __restrict__ rm)
{
    int j = threadIdx.x;
    int t = idx2[j >> 2] * 4 + (j & 3);
    rm[j] = idx1[t >> 4] * 16 + (t & 15);
}

__global__ __launch_bounds__(256) void zm_stats(
    const float* __restrict__ s, int n, float* __restrict__ out)
{
    __shared__ float red[256];
    const int tid = threadIdx.x;
    float mx = -3.4e38f;
    for (int i = tid; i < n; i += 256) mx = fmaxf(mx, s[i]);
    red[tid] = mx;
    __syncthreads();
    for (int o = 128; o > 0; o >>= 1) {
        if (tid < o) red[tid] = fmaxf(red[tid], red[tid + o]);
        __syncthreads();
    }
    mx = red[0];
    __syncthreads();
    float z = 0.0f;
    for (int i = tid; i < n; i += 256) z += expf(s[i] - mx);
    red[tid] = z;
    __syncthreads();
    for (int o = 128; o > 0; o >>= 1) {
        if (tid < o) red[tid] += red[tid + o];
        __syncthreads();
    }
    if (tid == 0) { out[0] = mx; out[1] = red[0]; }
}

__global__ void zm_zero(float* __restrict__ p, int n)
{
    int i = blockIdx.x * blockDim.x + threadIdx.x;
    if (i < n) p[i] = 0.0f;
}

__global__ __launch_bounds__(256) void zm_wsum(
    const float* __restrict__ h, const float* __restrict__ s,
    const float* __restrict__ st, int rpb, float* __restrict__ Mout)
{
    const int tid = threadIdx.x;
    const int r0 = blockIdx.x * rpb;
    const float mx = st[0];
    const float invZ = 1.0f / st[1];
    float a0 = 0.0f, a1 = 0.0f;
    for (int r = 0; r < rpb; r++) {
        int n = r0 + r;
        float w = expf(s[n] - mx) * invZ;
        a0 += w * h[(size_t)n * 512 + tid];
        a1 += w * h[(size_t)n * 512 + 256 + tid];
    }
    atomicAdd(&Mout[tid], a0);
    atomicAdd(&Mout[tid + 256], a1);
}

__global__ __launch_bounds__(256) void zm_logits(
    const float* __restrict__ M, const float* __restrict__ Wh,
    const float* __restrict__ bh, float* __restrict__ out)
{
    const int tid = threadIdx.x;
    const int c = tid >> 6, lane = tid & 63;
    float p = 0.0f;
    for (int f = lane; f < 512; f += 64) p += M[f] * Wh[f * 4 + c];
    for (int o = 32; o > 0; o >>= 1) p += __shfl_down(p, o);
    if (lane == 0) out[c] = p + bh[c];
}

extern "C" void kernel_launch(void* const* d_in, const int* in_sizes, int n_in,
                              void* d_out, int out_size, void* d_ws, size_t ws_size,
                              hipStream_t stream)
{
    const float* x1   = (const float*)d_in[0];   // 4096 x 1024
    const float* x2   = (const float*)d_in[1];   // 16384 x 1024
    const float* x3   = (const float*)d_in[2];   // 65536 x 1024
    const float* fcW  = (const float*)d_in[3];   // 3 x 1024 x 512
    const float* fcb  = (const float*)d_in[4];   // 3 x 512
    const float* gaWa = (const float*)d_in[5];   // 5 x 512 x 256
    const float* gaba = (const float*)d_in[6];   // 5 x 256
    const float* gaWb = (const float*)d_in[7];   // 5 x 512 x 256
    const float* gabb = (const float*)d_in[8];   // 5 x 256
    const float* gaWc = (const float*)d_in[9];   // 5 x 256 x 1
    const float* gabc = (const float*)d_in[10];  // 5 x 1
    const float* Wh   = (const float*)d_in[11];  // 512 x 4
    const float* bh   = (const float*)d_in[12];  // 4
    float* out = (float*)d_out;                  // 1 x 4

    // workspace layout
    char* p = (char*)d_ws;
    float*  h1f  = (float*)p;            p += (size_t)4096 * 512 * 4;
    float*  T1   = (float*)p;            p += (size_t)4096 * 1024 * 4;
    float*  h2f  = (float*)p;            p += (size_t)1024 * 512 * 4;
    float*  h3f  = (float*)p;            p += (size_t)1024 * 512 * 4;
    ushort* h1b  = (ushort*)p;           p += (size_t)4096 * 512 * 2;
    ushort* h2b  = (ushort*)p;           p += (size_t)1024 * 512 * 2;
    ushort* h3b  = (ushort*)p;           p += (size_t)1024 * 512 * 2;
    ushort* fc_t = (ushort*)p;           p += (size_t)3 * 512 * 1024 * 2;
    ushort* g_low  = (ushort*)p;         p += (size_t)1024 * 512 * 2;
    ushort* g_mid  = (ushort*)p;         p += (size_t)1024 * 512 * 2;
    ushort* g_high = (ushort*)p;         p += (size_t)512 * 512 * 2;
    float*  bl   = (float*)p;            p += 1024 * 4;
    float*  bm   = (float*)p;            p += 1024 * 4;
    float*  bhg  = (float*)p;            p += 512 * 4;
    float*  s1   = (float*)p;            p += 4096 * 4;
    float*  s1a  = (float*)p;            p += 4096 * 4;
    float*  s2   = (float*)p;            p += 1024 * 4;
    float*  s2a  = (float*)p;            p += 1024 * 4;
    float*  s3   = (float*)p;            p += 1024 * 4;
    float*  st   = (float*)p;            p += 8 * 4;
    float*  Mbuf = (float*)p;            p += 512 * 4;
    int*    idx1 = (int*)p;              p += 256 * 4;
    int*    idx2 = (int*)p;              p += 256 * 4;
    int*    rm2  = (int*)p;              p += 1024 * 4;
    int*    rm3  = (int*)p;              p += 1024 * 4;

    // ---- prep: weight pack + bias pack + M zero ----
    zm_pack<<<2816, 256, 0, stream>>>(fcW, gaWa, gaWb, fc_t, g_low, g_mid, g_high);
    zm_packbias<<<1, 1024, 0, stream>>>(gaba, gabb, bl, bm, bhg);
    zm_zero<<<1, 512, 0, stream>>>(Mbuf, 512);

    // ---- low mag ----
    zm_mgemm<0><<<dim3(8, 32), 256, 0, stream>>>(x1, 1024, nullptr, fc_t, fcb,
                                                 h1f, 512, h1b, 1024, 1);
    zm_mgemm<1><<<dim3(16, 32), 256, 0, stream>>>(h1b, 512, nullptr, g_low, bl,
                                                  T1, 1024, nullptr, 512, 0);
    zm_ga_combine<<<1024, 256, 0, stream>>>(T1, 1024, gaWc + 0 * 256, gabc + 0, s1);
    zm_ga_combine<<<1024, 256, 0, stream>>>(T1 + 512, 1024, gaWc + 3 * 256, gabc + 3, s1a);
    zm_topk<<<1, 512, 0, stream>>>(s1a, 4096, idx1);
    zm_mapgen2<<<1, 1024, 0, stream>>>(idx1, rm2);

    // ---- mid mag ----
    zm_mgemm<0><<<dim3(8, 8), 256, 0, stream>>>(x2, 1024, rm2, fc_t + 512 * 1024,
                                                fcb + 512, h2f, 512, h2b, 1024, 1);
    zm_mgemm<1><<<dim3(16, 8), 256, 0, stream>>>(h2b, 512, nullptr, g_mid, bm,
                                                 T1, 1024, nullptr, 512, 0);
    zm_ga_combine<<<256, 256, 0, stream>>>(T1, 1024, gaWc + 1 * 256, gabc + 1, s2);
    zm_ga_combine<<<256, 256, 0, stream>>>(T1 + 512, 1024, gaWc + 4 * 256, gabc + 4, s2a);
    zm_topk<<<1, 512, 0, stream>>>(s2a, 1024, idx2);
    zm_mapgen3<<<1, 1024, 0, stream>>>(idx1, idx2, rm3);

    // ---- high mag ----
    zm_mgemm<0><<<dim3(8, 8), 256, 0, stream>>>(x3, 1024, rm3, fc_t + 2 * 512 * 1024,
                                                fcb + 1024, h3f, 512, h3b, 1024, 1);
    zm_mgemm<1><<<dim3(8, 8), 256, 0, stream>>>(h3b, 512, nullptr, g_high, bhg,
                                                T1, 512, nullptr, 512, 0);
    zm_ga_combine<<<256, 256, 0, stream>>>(T1, 512, gaWc + 2 * 256, gabc + 2, s3);

    // ---- pooling + head ----
    zm_stats<<<1, 256, 0, stream>>>(s1, 4096, st + 0);
    zm_stats<<<1, 256, 0, stream>>>(s2, 1024, st + 2);
    zm_stats<<<1, 256, 0, stream>>>(s3, 1024, st + 4);
    zm_wsum<<<64, 256, 0, stream>>>(h1f, s1, st + 0, 64, Mbuf);
    zm_wsum<<<16, 256, 0, stream>>>(h2f, s2, st + 2, 64, Mbuf);
    zm_wsum<<<16, 256, 0, stream>>>(h3f, s3, st + 4, 64, Mbuf);
    zm_logits<<<1, 256, 0, stream>>>(Mbuf, Wh, bh, out);
}

// Round 3
// 604.471 us; speedup vs baseline: 1.8546x; 1.1982x over previous
//
#include <hip/hip_runtime.h>
#include <hip/hip_bf16.h>
#include <math.h>

// ---------------------------------------------------------------------------
// ZoomMIL round 3: fused pipeline, 10 dispatches.
//  - gating GEMM + tanh*sigmoid*Wc fused via interleaved weight packing
//  - split-K h-GEMMs for mid/high (fp32 atomic accumulate, relu deferred)
//  - topk(+rowmap)+stats fused 2-block kernels; stats3 in sgemm-high tail
//  - wsum+logits fused with device-scope completion counter
// ---------------------------------------------------------------------------

typedef __attribute__((ext_vector_type(8))) short short8;
typedef __attribute__((ext_vector_type(4))) float float4a;

__device__ __forceinline__ ushort f2bf(float f) {
    unsigned u = __float_as_uint(f);
    return (ushort)((u + 0x7fffu + ((u >> 16) & 1u)) >> 16);
}
__device__ __forceinline__ uint pk2(float a, float b) {
    __hip_bfloat162 t = __float22bfloat162_rn(make_float2(a, b));
    uint u; __builtin_memcpy(&u, &t, 4); return u;
}
__device__ __forceinline__ float aload(const float* p) {
    return __hip_atomic_load(p, __ATOMIC_RELAXED, __HIP_MEMORY_SCOPE_AGENT);
}

// ---------------------------------------------------------------------------
// h-GEMM: C = relu(A[rowmap] @ Bt^T + bias). BM=128,BN=64,BK=32, 4 waves 2x2.
// SPLIT=1: blockIdx.z picks K-chunk of 256; atomicAdd fp32 partials, no relu.
// ---------------------------------------------------------------------------
template<int SPLIT>
__global__ __launch_bounds__(256) void zm_hgemm(
    const float* __restrict__ A, int lda,
    const int* __restrict__ rowmap,
    const ushort* __restrict__ Bt,   // [N][K] bf16
    const float* __restrict__ bias,
    float* __restrict__ Cf, ushort* __restrict__ Cb, int ldc, int K)
{
    __shared__ ushort As[128 * 40];
    __shared__ ushort Bs[64 * 40];
    const int tid = threadIdx.x;
    const int brow = blockIdx.y << 7;
    const int bcol = blockIdx.x << 6;
    const int kbeg = SPLIT ? ((int)blockIdx.z << 8) : 0;
    const int kend = SPLIT ? kbeg + 256 : K;

    const int sr = tid >> 1;            // A row 0..127
    const int sk = (tid & 1) << 4;      // A k-half
    int arow = brow + sr;
    if (rowmap) arow = rowmap[arow];
    const float* Ap = A + (size_t)arow * lda;

    const int bn = tid >> 2;            // B n 0..63
    const int bk = (tid & 3) << 3;
    const ushort* Bp = Bt + (size_t)(bcol + bn) * K + bk;

    const int w = tid >> 6;
    const int wm = (w >> 1) << 6;
    const int wn = (w & 1) << 5;
    const int lane = tid & 63;
    const int lm = lane & 15;
    const int lq = lane >> 4;

    float4a acc[4][2] = {};

    for (int k0 = kbeg; k0 < kend; k0 += 32) {
        const float* ap = Ap + k0 + sk;
        float4 v0 = *(const float4*)(ap);
        float4 v1 = *(const float4*)(ap + 4);
        float4 v2 = *(const float4*)(ap + 8);
        float4 v3 = *(const float4*)(ap + 12);
        uint4 p0, p1;
        p0.x = pk2(v0.x, v0.y); p0.y = pk2(v0.z, v0.w);
        p0.z = pk2(v1.x, v1.y); p0.w = pk2(v1.z, v1.w);
        p1.x = pk2(v2.x, v2.y); p1.y = pk2(v2.z, v2.w);
        p1.z = pk2(v3.x, v3.y); p1.w = pk2(v3.z, v3.w);
        *(uint4*)&As[sr * 40 + sk]     = p0;
        *(uint4*)&As[sr * 40 + sk + 8] = p1;
        *(uint4*)&Bs[bn * 40 + bk] = *(const uint4*)(Bp + k0);
        __syncthreads();
        short8 afr[4], bfr[2];
#pragma unroll
        for (int mt = 0; mt < 4; mt++)
            afr[mt] = *(const short8*)&As[(wm + mt * 16 + lm) * 40 + lq * 8];
#pragma unroll
        for (int nt = 0; nt < 2; nt++)
            bfr[nt] = *(const short8*)&Bs[(wn + nt * 16 + lm) * 40 + lq * 8];
#pragma unroll
        for (int mt = 0; mt < 4; mt++)
#pragma unroll
            for (int nt = 0; nt < 2; nt++)
                acc[mt][nt] = __builtin_amdgcn_mfma_f32_16x16x32_bf16(
                    afr[mt], bfr[nt], acc[mt][nt], 0, 0, 0);
        __syncthreads();
    }

#pragma unroll
    for (int mt = 0; mt < 4; mt++) {
#pragma unroll
        for (int nt = 0; nt < 2; nt++) {
            int gc = bcol + wn + nt * 16 + lm;
            float bv = bias[gc];
            if (SPLIT && blockIdx.z != 0) bv = 0.0f;
#pragma unroll
            for (int r = 0; r < 4; r++) {
                int gr = brow + wm + mt * 16 + lq * 4 + r;
                float v = acc[mt][nt][r] + bv;
                if (SPLIT) {
                    atomicAdd(&Cf[(size_t)gr * ldc + gc], v);
                } else {
                    v = fmaxf(v, 0.0f);
                    Cf[(size_t)gr * ldc + gc] = v;
                    Cb[(size_t)gr * ldc + gc] = f2bf(v);
                }
            }
        }
    }
}

// ---------------------------------------------------------------------------
// Fused score GEMM: interleaved gating weights (even col=Wa, odd=Wb).
// BM=64,BN=64,BK=32, 4 waves side-by-side. Epilogue: tanh/sigmoid pairing via
// shfl_xor(1), *Wc, lane-reduce, LDS wave-combine, atomicAdd to score vec.
// AMODE 0: A bf16; AMODE 1: A fp32 + relu on stage.
// If statsOut != null: last finishing block computes softmax stats of sMain
// (n=1024) -> statsOut[0..1].
// ---------------------------------------------------------------------------
template<int AMODE>
__global__ __launch_bounds__(256) void zm_sgemm(
    const void* __restrict__ Av, int lda,
    const ushort* __restrict__ Bt,    // [N][512] interleaved bf16
    const float* __restrict__ bint,   // [N] interleaved biases
    const float* __restrict__ wc0, const float* __restrict__ wc1,
    float* __restrict__ sMain, float* __restrict__ sAux,
    float* __restrict__ statsOut, int* __restrict__ cnt2, int lastBlk)
{
    __shared__ ushort As[64 * 40];
    __shared__ ushort Bs[64 * 40];
    __shared__ float part[4][64];
    const int tid = threadIdx.x;
    const int brow = blockIdx.y << 6;
    const int bcol = blockIdx.x << 6;

    const int sr = tid >> 2;           // 0..63
    const int sk = (tid & 3) << 3;     // 0,8,16,24
    const float*  Af = (const float*)Av;
    const ushort* Ab = (const ushort*)Av;
    const ushort* Bp = Bt + (size_t)(bcol + sr) * 512 + sk;

    const int w = tid >> 6;
    const int wn = w << 4;
    const int lane = tid & 63;
    const int lm = lane & 15;
    const int lq = lane >> 4;

    float4a acc[4] = {};

    for (int k0 = 0; k0 < 512; k0 += 32) {
        if (AMODE == 0) {
            *(uint4*)&As[sr * 40 + sk] =
                *(const uint4*)(Ab + (size_t)(brow + sr) * lda + k0 + sk);
        } else {
            const float* ap = Af + (size_t)(brow + sr) * lda + k0 + sk;
            float4 v0 = *(const float4*)ap;
            float4 v1 = *(const float4*)(ap + 4);
            v0.x = fmaxf(v0.x, 0.f); v0.y = fmaxf(v0.y, 0.f);
            v0.z = fmaxf(v0.z, 0.f); v0.w = fmaxf(v0.w, 0.f);
            v1.x = fmaxf(v1.x, 0.f); v1.y = fmaxf(v1.y, 0.f);
            v1.z = fmaxf(v1.z, 0.f); v1.w = fmaxf(v1.w, 0.f);
            uint4 pk;
            pk.x = pk2(v0.x, v0.y); pk.y = pk2(v0.z, v0.w);
            pk.z = pk2(v1.x, v1.y); pk.w = pk2(v1.z, v1.w);
            *(uint4*)&As[sr * 40 + sk] = pk;
        }
        *(uint4*)&Bs[sr * 40 + sk] = *(const uint4*)(Bp + k0);
        __syncthreads();
        short8 bfr = *(const short8*)&Bs[(wn + lm) * 40 + lq * 8];
#pragma unroll
        for (int mt = 0; mt < 4; mt++) {
            short8 afr = *(const short8*)&As[(mt * 16 + lm) * 40 + lq * 8];
            acc[mt] = __builtin_amdgcn_mfma_f32_16x16x32_bf16(afr, bfr, acc[mt], 0, 0, 0);
        }
        __syncthreads();
    }

    const int gc = bcol + wn + lm;
    const float* wcp = (gc >= 512) ? wc1 : wc0;
    const float wcv = wcp[(gc & 511) >> 1];
    const float bv = bint[gc];
    const bool odd = (gc & 1);
    float* sp = (bcol >= 512) ? sAux : sMain;

#pragma unroll
    for (int mt = 0; mt < 4; mt++) {
        float red[4];
#pragma unroll
        for (int r = 0; r < 4; r++) {
            float v = acc[mt][r] + bv;
            float x = odd ? (1.0f / (1.0f + expf(-v))) : tanhf(v);
            float prt = __shfl_xor(x, 1);
            float ctr = odd ? 0.0f : (x * prt * wcv);
            ctr += __shfl_xor(ctr, 1);
            ctr += __shfl_xor(ctr, 2);
            ctr += __shfl_xor(ctr, 4);
            ctr += __shfl_xor(ctr, 8);
            red[r] = ctr;
        }
        if (lm == 0) {
#pragma unroll
            for (int r = 0; r < 4; r++) part[w][mt * 16 + lq * 4 + r] = red[r];
        }
    }
    __syncthreads();
    if (tid < 64) {
        float tot = part[0][tid] + part[1][tid] + part[2][tid] + part[3][tid];
        atomicAdd(&sp[brow + tid], tot);
    }

    // optional fused softmax-stats over sMain[0..1023] by last finishing block
    if (statsOut) {
        __threadfence();
        __shared__ int lastf;
        if (tid == 0)
            lastf = (__hip_atomic_fetch_add(cnt2, 1, __ATOMIC_ACQ_REL,
                                            __HIP_MEMORY_SCOPE_AGENT) == lastBlk);
        __syncthreads();
        if (lastf) {
            float* red = (float*)part;   // 256 floats
            float vv[4];
            float mx = -3.4e38f;
#pragma unroll
            for (int j = 0; j < 4; j++) {
                vv[j] = aload(&sMain[tid + j * 256]);
                mx = fmaxf(mx, vv[j]);
            }
            red[tid] = mx; __syncthreads();
            for (int o = 128; o > 0; o >>= 1) {
                if (tid < o) red[tid] = fmaxf(red[tid], red[tid + o]);
                __syncthreads();
            }
            mx = red[0]; __syncthreads();
            float z = 0.0f;
#pragma unroll
            for (int j = 0; j < 4; j++) z += expf(vv[j] - mx);
            red[tid] = z; __syncthreads();
            for (int o = 128; o > 0; o >>= 1) {
                if (tid < o) red[tid] += red[tid + o];
                __syncthreads();
            }
            if (tid == 0) { statsOut[0] = mx; statsOut[1] = red[0]; }
        }
    }
}

// ---------------------------------------------------------------------------
// top-256 (+ rowmap gen) and softmax stats, fused: grid=2 blocks of 1024.
// block0: bitonic topk of sa[0..n), write idx_out + rm_out.
//   rm_out[j] = t where t = idx[j/4]*4 + j%4, then through idx_prev if given.
// block1: stats of sm -> stOut[0..1].
// ---------------------------------------------------------------------------
__global__ __launch_bounds__(1024) void zm_topk(
    const float* __restrict__ sa, const float* __restrict__ sm, int n,
    const int* __restrict__ idx_prev,
    int* __restrict__ idx_out, int* __restrict__ rm_out,
    float* __restrict__ stOut)
{
    __shared__ unsigned long long keys[4096];
    const int bs = 1024;
    const int tid = threadIdx.x;

    if (blockIdx.x == 1) {
        float* red = (float*)keys;
        float mx = -3.4e38f;
        for (int i = tid; i < n; i += bs) mx = fmaxf(mx, sm[i]);
        red[tid] = mx; __syncthreads();
        for (int o = 512; o > 0; o >>= 1) {
            if (tid < o) red[tid] = fmaxf(red[tid], red[tid + o]);
            __syncthreads();
        }
        mx = red[0]; __syncthreads();
        float z = 0.0f;
        for (int i = tid; i < n; i += bs) z += expf(sm[i] - mx);
        red[tid] = z; __syncthreads();
        for (int o = 512; o > 0; o >>= 1) {
            if (tid < o) red[tid] += red[tid + o];
            __syncthreads();
        }
        if (tid == 0) { stOut[0] = mx; stOut[1] = red[0]; }
        return;
    }

    for (int i = tid; i < n; i += bs) {
        unsigned u = __float_as_uint(sa[i]);
        u = (u & 0x80000000u) ? ~u : (u | 0x80000000u);
        keys[i] = ((unsigned long long)(~u) << 32) | (unsigned)i;
    }
    __syncthreads();
    for (int k2 = 2; k2 <= n; k2 <<= 1) {
        for (int j = k2 >> 1; j > 0; j >>= 1) {
            for (int i = tid; i < n; i += bs) {
                int ixj = i ^ j;
                if (ixj > i) {
                    unsigned long long a = keys[i], b = keys[ixj];
                    bool up = ((i & k2) == 0);
                    if ((a > b) == up) { keys[i] = b; keys[ixj] = a; }
                }
            }
            __syncthreads();
        }
    }
    int v = 0;
    if (tid < 256) v = (int)(keys[tid] & 0xffffffffu);
    __syncthreads();
    int* ik = (int*)keys;
    if (tid < 256) ik[tid] = v;
    __syncthreads();
    for (int k2 = 2; k2 <= 256; k2 <<= 1) {
        for (int j = k2 >> 1; j > 0; j >>= 1) {
            for (int i = tid; i < 256; i += bs) {
                int ixj = i ^ j;
                if (ixj > i) {
                    int a = ik[i], b = ik[ixj];
                    bool up = ((i & k2) == 0);
                    if ((a > b) == up) { ik[i] = b; ik[ixj] = a; }
                }
            }
            __syncthreads();
        }
    }
    if (tid < 256) idx_out[tid] = ik[tid];
    int t = ik[tid >> 2] * 4 + (tid & 3);
    rm_out[tid] = idx_prev ? (idx_prev[t >> 4] * 16 + (t & 15)) : t;
}

// ---------------------------------------------------------------------------
// prep: weight transpose-pack (fc + interleaved gating), bias pack, zeroing.
// grid = 1536 (fc tiles) + 1280 (gating tiles) + 1 (bias) + 64 (zero) = 2881
// ---------------------------------------------------------------------------
__global__ __launch_bounds__(256) void zm_prep(
    const float* __restrict__ fcW,
    const float* __restrict__ gaWa, const float* __restrict__ gaWb,
    const float* __restrict__ gaba, const float* __restrict__ gabb,
    ushort* __restrict__ fc_t, ushort* __restrict__ gint,
    float* __restrict__ bint, float4* __restrict__ zbase, int zn4)
{
    const int b = blockIdx.x;
    const int tid = threadIdx.x;
    if (b >= 2817) {
        float4 z4 = make_float4(0.f, 0.f, 0.f, 0.f);
        for (int i = (b - 2817) * 256 + tid; i < zn4; i += 64 * 256)
            zbase[i] = z4;
        return;
    }
    if (b == 2816) {
        for (int i = tid; i < 2560; i += 256) {
            int n, head;
            if (i < 1024)      { n = i;        head = (n >> 9) ? 3 : 0; }
            else if (i < 2048) { n = i - 1024; head = (n >> 9) ? 4 : 1; }
            else               { n = i - 2048; head = 2; }
            int h = (n & 511) >> 1;
            const float* src = (n & 1) ? gabb : gaba;
            bint[i] = src[head * 256 + h];
        }
        return;
    }
    __shared__ ushort tile[32][33];
    const int c = tid & 31, r8 = tid >> 5;
    if (b < 1536) {
        int mat = b >> 9, rem = b & 511;
        int tk = rem >> 4, tn = rem & 15;
        const float* src = fcW + (size_t)mat * 1024 * 512;
        ushort* dst = fc_t + (size_t)mat * 512 * 1024;
        int k0 = tk * 32, n0 = tn * 32;
#pragma unroll
        for (int it = 0; it < 4; it++) {
            int r = r8 + it * 8;
            tile[r][c] = f2bf(src[(size_t)(k0 + r) * 512 + n0 + c]);
        }
        __syncthreads();
#pragma unroll
        for (int it = 0; it < 4; it++) {
            int r = r8 + it * 8;
            dst[(size_t)(n0 + r) * 1024 + k0 + c] = tile[c][r];
        }
    } else {
        int idx = b - 1536;
        int mat = idx >> 7, rem = idx & 127;
        int tk = rem >> 3, th = rem & 7;
        int head = mat >> 1, br = mat & 1;
        const float* src = (br ? gaWb : gaWa) + (size_t)head * 512 * 256;
        ushort* dstb; int off;
        if (head == 0)      { dstb = gint;              off = 0;   }
        else if (head == 1) { dstb = gint + 1024 * 512; off = 0;   }
        else if (head == 2) { dstb = gint + 2048 * 512; off = 0;   }
        else if (head == 3) { dstb = gint;              off = 512; }
        else                { dstb = gint + 1024 * 512; off = 512; }
        int k0 = tk * 32, h0 = th * 32;
#pragma unroll
        for (int it = 0; it < 4; it++) {
            int r = r8 + it * 8;
            tile[r][c] = f2bf(src[(size_t)(k0 + r) * 256 + h0 + c]);
        }
        __syncthreads();
#pragma unroll
        for (int it = 0; it < 4; it++) {
            int r = r8 + it * 8;  // local h
            dstb[(size_t)(off + 2 * (h0 + r) + br) * 512 + k0 + c] = tile[c][r];
        }
    }
}

// ---------------------------------------------------------------------------
// final: softmax-weighted pooling of all 3 levels into M (atomics), last
// block computes logits. grid = 96 x 256.
// ---------------------------------------------------------------------------
__global__ __launch_bounds__(256) void zm_final(
    const float* __restrict__ h1f, const float* __restrict__ h2f,
    const float* __restrict__ h3f,
    const float* __restrict__ s1, const float* __restrict__ s2,
    const float* __restrict__ s3,
    const float* __restrict__ st, float* __restrict__ Mbuf,
    int* __restrict__ cnt,
    const float* __restrict__ Wh, const float* __restrict__ bh,
    float* __restrict__ out)
{
    const int tid = threadIdx.x;
    const int b = blockIdx.x;
    const float* h; const float* s; const float* stp; int r0, rl;
    if (b < 64)      { h = h1f; s = s1; stp = st;     r0 = b * 64;        rl = 0; }
    else if (b < 80) { h = h2f; s = s2; stp = st + 2; r0 = (b - 64) * 64; rl = 1; }
    else             { h = h3f; s = s3; stp = st + 4; r0 = (b - 80) * 64; rl = 1; }
    const float mx = stp[0];
    const float invZ = 1.0f / stp[1];
    float a0 = 0.0f, a1 = 0.0f;
    for (int r = 0; r < 64; r++) {
        int n = r0 + r;
        float wgt = expf(s[n] - mx) * invZ;
        float v0 = h[(size_t)n * 512 + tid];
        float v1 = h[(size_t)n * 512 + 256 + tid];
        if (rl) { v0 = fmaxf(v0, 0.f); v1 = fmaxf(v1, 0.f); }
        a0 += wgt * v0; a1 += wgt * v1;
    }
    atomicAdd(&Mbuf[tid], a0);
    atomicAdd(&Mbuf[tid + 256], a1);
    __threadfence();
    __shared__ int lastf;
    if (tid == 0)
        lastf = (__hip_atomic_fetch_add(cnt, 1, __ATOMIC_ACQ_REL,
                                        __HIP_MEMORY_SCOPE_AGENT) == 95);
    __syncthreads();
    if (lastf) {
        const int c = tid >> 6, lane = tid & 63;
        float pacc = 0.0f;
        for (int f = lane; f < 512; f += 64)
            pacc += aload(&Mbuf[f]) * Wh[f * 4 + c];
        for (int o = 32; o > 0; o >>= 1) pacc += __shfl_down(pacc, o);
        if (lane == 0) out[c] = pacc + bh[c];
    }
}

extern "C" void kernel_launch(void* const* d_in, const int* in_sizes, int n_in,
                              void* d_out, int out_size, void* d_ws, size_t ws_size,
                              hipStream_t stream)
{
    const float* x1   = (const float*)d_in[0];
    const float* x2   = (const float*)d_in[1];
    const float* x3   = (const float*)d_in[2];
    const float* fcW  = (const float*)d_in[3];
    const float* fcb  = (const float*)d_in[4];
    const float* gaWa = (const float*)d_in[5];
    const float* gaba = (const float*)d_in[6];
    const float* gaWb = (const float*)d_in[7];
    const float* gabb = (const float*)d_in[8];
    const float* gaWc = (const float*)d_in[9];
    // gabc (d_in[10]) dropped: softmax/top-k are shift-invariant
    const float* Wh   = (const float*)d_in[11];
    const float* bh   = (const float*)d_in[12];
    float* out = (float*)d_out;

    char* p = (char*)d_ws;
    float*  h1f  = (float*)p;
    ushort* h1b  = (ushort*)(p + 8388608);
    ushort* fc_t = (ushort*)(p + 12582912);
    ushort* gint = (ushort*)(p + 15728640);
    float*  bint = (float*)(p + 18350080);
    float*  st   = (float*)(p + 18360320);
    int*    idx1 = (int*)(p + 18360352);
    int*    idx2 = (int*)(p + 18361376);
    int*    rm2  = (int*)(p + 18362400);
    int*    rm3  = (int*)(p + 18366496);
    char*   zbase = p + 18370592;            // zero region start
    float*  h2f  = (float*)zbase;
    float*  h3f  = (float*)(zbase + 2097152);
    float*  s1   = (float*)(zbase + 4194304);
    float*  s1a  = (float*)(zbase + 4210688);
    float*  s2   = (float*)(zbase + 4227072);
    float*  s2a  = (float*)(zbase + 4231168);
    float*  s3   = (float*)(zbase + 4235264);
    float*  Mbuf = (float*)(zbase + 4239360);
    int*    cnt  = (int*)(zbase + 4241408);  // [0]=final, [1]=sgemm-high
    const int ZN4 = 4241424 / 16;

    // 1. prep: pack weights/biases, zero accumulators
    zm_prep<<<2881, 256, 0, stream>>>(fcW, gaWa, gaWb, gaba, gabb,
                                      fc_t, gint, bint, (float4*)zbase, ZN4);
    // 2-3. low mag
    zm_hgemm<0><<<dim3(8, 32), 256, 0, stream>>>(x1, 1024, nullptr, fc_t, fcb,
                                                 h1f, h1b, 512, 1024);
    zm_sgemm<0><<<dim3(16, 64), 256, 0, stream>>>(h1b, 512, gint, bint,
                                                  gaWc, gaWc + 3 * 256,
                                                  s1, s1a, nullptr, nullptr, 0);
    // 4. topk low (+stats s1)
    zm_topk<<<2, 1024, 0, stream>>>(s1a, s1, 4096, nullptr, idx1, rm2, st);
    // 5-6. mid mag
    zm_hgemm<1><<<dim3(8, 8, 4), 256, 0, stream>>>(x2, 1024, rm2,
                                                   fc_t + 512 * 1024, fcb + 512,
                                                   h2f, nullptr, 512, 1024);
    zm_sgemm<1><<<dim3(16, 16), 256, 0, stream>>>(h2f, 512, gint + 1024 * 512,
                                                  bint + 1024,
                                                  gaWc + 256, gaWc + 4 * 256,
                                                  s2, s2a, nullptr, nullptr, 0);
    // 7. topk mid (+stats s2)
    zm_topk<<<2, 1024, 0, stream>>>(s2a, s2, 1024, idx1, idx2, rm3, st + 2);
    // 8-9. high mag (sgemm fuses stats s3 via counter)
    zm_hgemm<1><<<dim3(8, 8, 4), 256, 0, stream>>>(x3, 1024, rm3,
                                                   fc_t + 2 * 512 * 1024, fcb + 1024,
                                                   h3f, nullptr, 512, 1024);
    zm_sgemm<1><<<dim3(8, 16), 256, 0, stream>>>(h3f, 512, gint + 2048 * 512,
                                                 bint + 2048,
                                                 gaWc + 2 * 256, gaWc + 2 * 256,
                                                 s3, s3, st + 4, cnt + 1, 127);
    // 10. pooling + logits
    zm_final<<<96, 256, 0, stream>>>(h1f, h2f, h3f, s1, s2, s3, st, Mbuf, cnt,
                                     Wh, bh, out);
}